// Round 6
// baseline (104.598 us; speedup 1.0000x reference)
//
#include <hip/hip_runtime.h>

#define HH 256
#define WW 256
#define NPIX (2 * HH * WW)   // 131072 (B=2)
#define NC 48
#define NB 31
#define OT 32         // output tile (32x32 per block)
#define PT 38         // phi tile = OT+6
#define PSTR 44       // phi LDS row stride (16B aligned, conflict-free)
#define UT 44         // u tile = OT+12
#define USTR 52       // u LDS row stride (16B aligned, conflict-free)
#define TP 192        // table pairs per channel: x in [-1.5,1.5], h=1/64

// r20: r18/r19 both died on container acquisition (no compile error, no
// pytest, no timing block) -- audit found no kernel-side container-killer,
// but per rigor discipline this round is MINIMAL-DELTA from r17 (the last
// source that provably ran at 99.9us): device code is byte-identical to
// r17; only the host launch changes, instantiating tnrd_main<2> (NG=24,
// 3072 blocks) to pull the grid-granularity half of the occupancy lever.
// Residency stays VGPR-capped at 6 blocks/CU (512/84); the r18 VGPR
// squeeze (pipeline removal + launch_bounds(256,7)) is queued separately.
// If this fails too, it is conclusively infra (r17 ran this exact code).
// Hard-won constraints (do not violate):
//  - all per-lane accumulators NAMED SCALARS (r3: arrays -> 700 MB spill)
//  - 2 channels/pass, dy loop unroll-pinned (r5: 4ch+unroll -> VALU +40%)
//  - 4-px items, 12-float window (r6: 8-px items -> 300 MB spill)
//  - atomic combine is a 34 us loss (r13)
//  - gather pipe is speed-invariant LDS vs global (r14/r15 A/B)
//  - table-build fusion costs more than the launch it saves (r16)
//  - occupancy lever is real: r17 (6 vs 3 blocks/CU) = -14.8us

// ---- Build the 48 phi tables once as (value, delta) pairs for 1-read lerp.
__global__ __launch_bounds__(256)
void tnrd_table(const float* __restrict__ wr, float2* __restrict__ tab)
{
    const int ch = blockIdx.x;
    const float* rc = wr + ch * NB;
    for (int j = threadIdx.x; j < TP; j += 256) {
        float v0 = 0.f, v1 = 0.f;
        float x0 = fmaf((float)j, 1.0f / 64.0f, -1.5f);
        float x1 = x0 + 1.0f / 64.0f;
        #pragma unroll
        for (int k = 0; k < NB; ++k) {
            float mu = -1.f + (float)k * (1.f / 15.f);
            float d0 = x0 - mu, d1 = x1 - mu;
            float w = rc[k];
            v0 = fmaf(w, __expf(-50.f * d0 * d0), v0);
            v1 = fmaf(w, __expf(-50.f * d1 * d1), v1);
        }
        tab[ch * TP + j] = make_float2(v0, v1 - v0);
    }
}

// conv1 inner step: window scalars s0..s3, both channels' weights
#define F1STEP(WI, s0, s1, s2, s3)                                      \
    { float fa = wa[WI], fb = wb[WI];                                   \
      a0 = fmaf(s0, fa, a0); a1 = fmaf(s1, fa, a1);                     \
      a2 = fmaf(s2, fa, a2); a3 = fmaf(s3, fa, a3);                     \
      b0 = fmaf(s0, fb, b0); b1 = fmaf(s1, fb, b1);                     \
      b2 = fmaf(s2, fb, b2); b3 = fmaf(s3, fb, b3); }

// 7 taps over the 10-float window (q0.xyzw q1.xyzw q2.xy)
#define F1ROW(WA, WB, q0, q1, q2)                                       \
    { const float* wa = (WA); const float* wb = (WB);                   \
      F1STEP(0, q0.x, q0.y, q0.z, q0.w)                                 \
      F1STEP(1, q0.y, q0.z, q0.w, q1.x)                                 \
      F1STEP(2, q0.z, q0.w, q1.x, q1.y)                                 \
      F1STEP(3, q0.w, q1.x, q1.y, q1.z)                                 \
      F1STEP(4, q1.x, q1.y, q1.z, q1.w)                                 \
      F1STEP(5, q1.y, q1.z, q1.w, q2.x)                                 \
      F1STEP(6, q1.z, q1.w, q2.x, q2.y) }

// table lerp from global (L1-resident 18KB table), named temps only
#define LERP1(res, aval, T)                                             \
    { float t_ = fminf(fmaxf(fmaf(aval, 64.f, 96.f), 0.f), 191.999f);   \
      float fj_ = floorf(t_);                                           \
      float2 e_ = (T)[(int)fj_];            /* global_load_dwordx2 */   \
      res = fmaf(t_ - fj_, e_.y, e_.x); }

// conv2 inner step (flipped weights), both channels
#define C2STEP(WI, s0, s1, s2, s3, t0, t1, t2, t3)                      \
    { float fa = wra[WI], fb = wrb[WI];                                 \
      o0 = fmaf(s0, fa, o0); o1 = fmaf(s1, fa, o1);                     \
      o2 = fmaf(s2, fa, o2); o3 = fmaf(s3, fa, o3);                     \
      o0 = fmaf(t0, fb, o0); o1 = fmaf(t1, fb, o1);                     \
      o2 = fmaf(t2, fb, o2); o3 = fmaf(t3, fb, o3); }

template<int CPG>   // channels per group: 2 main, 4/8 fallback
__global__ __launch_bounds__(256, 6)
void tnrd_main(const float* __restrict__ u,
               const float* __restrict__ wf,    // filters [48][49]
               const float2* __restrict__ tab,  // phi tables [48][TP]
               float* __restrict__ part)
{
    constexpr int NGRP = NC / CPG;
    constexpr int NPASS = CPG / 2;
    __shared__ __align__(16) float u_s[UT * USTR];          //  9152 B
    __shared__ __align__(16) float phi_s[2][PT * PSTR];     // 13376 B

    const int tid = threadIdx.x;
    const int bx = blockIdx.x, by = blockIdx.y;
    const int b = blockIdx.z / NGRP, g = blockIdx.z % NGRP;
    const int c0g = g * CPG;

    // ---- stage u tile (6-halo, zero-padded incl. stride pad) ----
    const int uy0 = by * OT - 6, ux0 = bx * OT - 6;
    const float* ub = u + b * (HH * WW);
    for (int i = tid; i < UT * USTR; i += 256) {
        int r = i / USTR, c = i - r * USTR;
        int gy = uy0 + r, gx = ux0 + c;
        float v = 0.f;
        if (c < UT && (unsigned)gy < HH && (unsigned)gx < WW)
            v = ub[gy * WW + gx];
        u_s[i] = v;
    }
    __syncthreads();

    const int oy = tid >> 3;        // 0..31
    const int ox0 = (tid & 7) * 4;  // 0..28
    float o0 = 0.f, o1 = 0.f, o2 = 0.f, o3 = 0.f;
    const int py0 = by * OT - 3, px0 = bx * OT - 3;

    // ---- conv1 + RBF lerp for channel pair cp into planes bufA/bufB ----
    auto conv1_pass = [&](int cp, float* __restrict__ bufA,
                          float* __restrict__ bufB) {
        const float* wA = wf + (c0g + 2 * cp) * 49;   // block-uniform s_load
        const float* wB = wA + 49;
        const float2* tA = tab + (c0g + 2 * cp) * TP;     // global, L1-hot
        const float2* tB = tA + TP;
        // 380 items = 10 col-strips x 38 rows (column-major)
        for (int p = 0; p < 2; ++p) {
            const int gi = tid + p * 256;
            if (gi < PT * 10) {
                const int pr = gi % PT, pc = (gi / PT) * 4;
                float a0 = 0.f, a1 = 0.f, a2 = 0.f, a3 = 0.f;
                float b0 = 0.f, b1 = 0.f, b2 = 0.f, b3 = 0.f;
                const float* bptr = &u_s[pr * USTR + pc];

                // software pipeline: load row dy+1 before consuming row dy
                float4 c0 = *(const float4*)(bptr);
                float4 c1 = *(const float4*)(bptr + 4);
                float2 c2 = *(const float2*)(bptr + 8);
                #pragma unroll 1
                for (int dy = 0; dy < 6; ++dy) {
                    const float* nr = bptr + (dy + 1) * USTR;
                    float4 n0 = *(const float4*)(nr);
                    float4 n1 = *(const float4*)(nr + 4);
                    float2 n2 = *(const float2*)(nr + 8);
                    F1ROW(wA + dy * 7, wB + dy * 7, c0, c1, c2)
                    c0 = n0; c1 = n1; c2 = n2;
                }
                F1ROW(wA + 42, wB + 42, c0, c1, c2)   // epilogue dy=6

                // ---- 1-gather lerp; phi = 0 outside image ----
                const int gy = py0 + pr;
                const bool rowok = (unsigned)gy < HH;
                const bool ok0 = rowok && (unsigned)(px0 + pc + 0) < WW;
                const bool ok1 = rowok && (unsigned)(px0 + pc + 1) < WW;
                const bool ok2 = rowok && (unsigned)(px0 + pc + 2) < WW;
                const bool ok3 = rowok && (unsigned)(px0 + pc + 3) < WW;
                float pA0, pA1, pA2, pA3, pB0, pB1, pB2, pB3;
                LERP1(pA0, a0, tA) LERP1(pB0, b0, tB)
                LERP1(pA1, a1, tA) LERP1(pB1, b1, tB)
                LERP1(pA2, a2, tA) LERP1(pB2, b2, tB)
                LERP1(pA3, a3, tA) LERP1(pB3, b3, tB)
                pA0 = ok0 ? pA0 : 0.f;  pB0 = ok0 ? pB0 : 0.f;
                pA1 = ok1 ? pA1 : 0.f;  pB1 = ok1 ? pB1 : 0.f;
                pA2 = ok2 ? pA2 : 0.f;  pB2 = ok2 ? pB2 : 0.f;
                pA3 = ok3 ? pA3 : 0.f;  pB3 = ok3 ? pB3 : 0.f;
                *(float4*)(bufA + pr * PSTR + pc) =
                    make_float4(pA0, pA1, pA2, pA3);      // ds_write_b128
                *(float4*)(bufB + pr * PSTR + pc) =
                    make_float4(pB0, pB1, pB2, pB3);      // ds_write_b128
            }
        }
    };

    // single-buffered phi: conv1(p); sync; conv2(p); sync; ...
    #pragma unroll 1
    for (int pass = 0; pass < NPASS; ++pass) {
        conv1_pass(pass, phi_s[0], phi_s[1]);
        __syncthreads();

        // ---- conv2 accumulate pass's two channels (flipped weights) ----
        const float* wA = wf + (c0g + 2 * pass) * 49;
        const float* wB = wA + 49;
        const float* pA = phi_s[0];
        const float* pB = phi_s[1];
        for (int dy = 0; dy < 7; ++dy) {
            const float* rA = pA + (oy + dy) * PSTR + ox0;
            const float* rB = pB + (oy + dy) * PSTR + ox0;
            const float4 A0 = *(const float4*)(rA);
            const float4 A1 = *(const float4*)(rA + 4);
            const float2 A2 = *(const float2*)(rA + 8);
            const float4 B0 = *(const float4*)(rB);
            const float4 B1 = *(const float4*)(rB + 4);
            const float2 B2 = *(const float2*)(rB + 8);
            const float* wra = wA + (6 - dy) * 7;
            const float* wrb = wB + (6 - dy) * 7;
            C2STEP(6, A0.x, A0.y, A0.z, A0.w, B0.x, B0.y, B0.z, B0.w)
            C2STEP(5, A0.y, A0.z, A0.w, A1.x, B0.y, B0.z, B0.w, B1.x)
            C2STEP(4, A0.z, A0.w, A1.x, A1.y, B0.z, B0.w, B1.x, B1.y)
            C2STEP(3, A0.w, A1.x, A1.y, A1.z, B0.w, B1.x, B1.y, B1.z)
            C2STEP(2, A1.x, A1.y, A1.z, A1.w, B1.x, B1.y, B1.z, B1.w)
            C2STEP(1, A1.y, A1.z, A1.w, A2.x, B1.y, B1.z, B1.w, B2.x)
            C2STEP(0, A1.z, A1.w, A2.x, A2.y, B1.z, B1.w, B2.x, B2.y)
        }
        if (pass < NPASS - 1) __syncthreads();
    }

    const int gy = by * OT + oy, gx = bx * OT + ox0;
    float4 v4 = make_float4(o0, o1, o2, o3);
    *reinterpret_cast<float4*>(part + (size_t)g * NPIX + b * (HH * WW)
                               + gy * WW + gx) = v4;
}

template<int NGRP>
__global__ __launch_bounds__(256)
void combine_kernel(const float* __restrict__ u,
                    const float* __restrict__ f,
                    const float* __restrict__ lam,
                    const float* __restrict__ part,
                    float* __restrict__ out)
{
    int i = blockIdx.x * 256 + threadIdx.x;  // 512 blocks -> NPIX
    float d = 0.f;
    #pragma unroll
    for (int g = 0; g < NGRP; ++g) d += part[g * NPIX + i];
    float lv = lam[0];
    float uv = u[i];
    float fv = f[i];
    out[i] = uv - d - lv * (uv - fv);
}

extern "C" void kernel_launch(void* const* d_in, const int* in_sizes, int n_in,
                              void* d_out, int out_size, void* d_ws, size_t ws_size,
                              hipStream_t stream) {
    const float* u    = (const float*)d_in[0];
    const float* f    = (const float*)d_in[1];
    const float* filt = (const float*)d_in[2];
    const float* rbfw = (const float*)d_in[3];
    const float* lam  = (const float*)d_in[4];
    float* out = (float*)d_out;
    float* part = (float*)d_ws;
    // phi tables overlaid on d_out scratch (48*192 float2 = 18432 floats
    // <= 131072); combine_kernel fully overwrites d_out afterwards.
    float2* tabg = (float2*)d_out;

    tnrd_table<<<NC, 256, 0, stream>>>(rbfw, tabg);
    if (ws_size >= (size_t)24 * NPIX * sizeof(float)) {
        // 24 groups x 2ch: 3072 blocks (grid-granularity lever; residency
        // still VGPR-capped at 6 blocks/CU -- device code identical to r17)
        tnrd_main<2><<<dim3(8, 8, 48), 256, 0, stream>>>(u, filt, tabg, part);
        combine_kernel<24><<<512, 256, 0, stream>>>(u, f, lam, part, out);
    } else if (ws_size >= (size_t)12 * NPIX * sizeof(float)) {
        // r17 structure: 12 groups x 4ch, 6 blocks/CU
        tnrd_main<4><<<dim3(8, 8, 24), 256, 0, stream>>>(u, filt, tabg, part);
        combine_kernel<12><<<512, 256, 0, stream>>>(u, f, lam, part, out);
    } else {
        // smallest-ws fallback: 6 groups x 8ch (r15 structure)
        tnrd_main<8><<<dim3(8, 8, 12), 256, 0, stream>>>(u, filt, tabg, part);
        combine_kernel<6><<<512, 256, 0, stream>>>(u, f, lam, part, out);
    }
}

// Round 7
// 100.144 us; speedup vs baseline: 1.0445x; 1.0445x over previous
//
#include <hip/hip_runtime.h>

#define HH 256
#define WW 256
#define NPIX (2 * HH * WW)   // 131072 (B=2)
#define NC 48
#define NB 31
#define TP 192        // table pairs per channel: x in [-1.5,1.5], h=1/64

// ---- r21 main-path geometry: 32x64 output tile, 2x4 px per thread ----
#define OTY 32
#define OTX 64
#define PTY 38        // phi tile rows = OTY+6
#define PTX 70        // phi tile cols = OTX+6
#define PSTR2 76      // phi stride: 76*4B, 76%32=12 -> 8-period bank spread
#define UTY 44        // u tile rows = OTY+12
#define UTX 76        // u tile cols = OTX+12
#define USTR2 84      // u stride: 84*4B, 84%32=20 -> 8-period bank spread
#define N1ITEM 684    // conv1 items: 18 col-strips x 38 rows

// ---- legacy (fallback) geometry: 32x32 tile, 1x4 px per thread ----
#define OT 32
#define PT 38
#define PSTR 44
#define UT 44
#define USTR 52

// r21: work-per-thread attack. r20 facts: VGPR fell 84->36 (straight-line
// CPG=2), occupancy 24.6->50% but kernel 39->43.5us -- wave supply is NOT
// the bottleneck past ~16 waves/CU; duplicated per-block staging/barriers
// ate the gain. VALUBusy 48%, HBM 3.9%, FETCH 1.1MB (u is L2-resident).
// Fix: spend the 48 free VGPRs on a 2x4 output register tile (32x64-px
// blocks): conv2 LDS reads/px ~halved (8 row-loads feed 2 output rows),
// conv1 halo overcompute 1.41->1.30, staging+barriers/px halved, deeper
// ILP (8 indep accumulators). FMA order per accumulator preserved ->
// bit-identical (absmax 0.015625). LDS 37.9KB -> 4 blocks/CU = 16
// waves/CU = r20's measured effective occupancy.
// Hard-won constraints (do not violate):
//  - all per-lane accumulators NAMED SCALARS (r3: arrays -> 700 MB spill)
//  - conv1 dy loop unroll-pinned, SW row-pipeline kept (proven r17/r20)
//  - 4-px-wide items, 10-float window (r6: wider -> spill)
//  - atomic combine is a 34 us loss (r13)
//  - gather pipe speed-invariant LDS vs global (r14/r15); table fusion
//    loses (r16); occupancy lever saturates at ~16 waves/CU (r17/r20)

// ---- Build the 48 phi tables once as (value, delta) pairs for 1-read lerp.
__global__ __launch_bounds__(256)
void tnrd_table(const float* __restrict__ wr, float2* __restrict__ tab)
{
    const int ch = blockIdx.x;
    const float* rc = wr + ch * NB;
    for (int j = threadIdx.x; j < TP; j += 256) {
        float v0 = 0.f, v1 = 0.f;
        float x0 = fmaf((float)j, 1.0f / 64.0f, -1.5f);
        float x1 = x0 + 1.0f / 64.0f;
        #pragma unroll
        for (int k = 0; k < NB; ++k) {
            float mu = -1.f + (float)k * (1.f / 15.f);
            float d0 = x0 - mu, d1 = x1 - mu;
            float w = rc[k];
            v0 = fmaf(w, __expf(-50.f * d0 * d0), v0);
            v1 = fmaf(w, __expf(-50.f * d1 * d1), v1);
        }
        tab[ch * TP + j] = make_float2(v0, v1 - v0);
    }
}

// conv1 inner step: window scalars s0..s3, both channels' weights
#define F1STEP(WI, s0, s1, s2, s3)                                      \
    { float fa = wa[WI], fb = wb[WI];                                   \
      a0 = fmaf(s0, fa, a0); a1 = fmaf(s1, fa, a1);                     \
      a2 = fmaf(s2, fa, a2); a3 = fmaf(s3, fa, a3);                     \
      b0 = fmaf(s0, fb, b0); b1 = fmaf(s1, fb, b1);                     \
      b2 = fmaf(s2, fb, b2); b3 = fmaf(s3, fb, b3); }

// 7 taps over the 10-float window (q0.xyzw q1.xyzw q2.xy)
#define F1ROW(WA, WB, q0, q1, q2)                                       \
    { const float* wa = (WA); const float* wb = (WB);                   \
      F1STEP(0, q0.x, q0.y, q0.z, q0.w)                                 \
      F1STEP(1, q0.y, q0.z, q0.w, q1.x)                                 \
      F1STEP(2, q0.z, q0.w, q1.x, q1.y)                                 \
      F1STEP(3, q0.w, q1.x, q1.y, q1.z)                                 \
      F1STEP(4, q1.x, q1.y, q1.z, q1.w)                                 \
      F1STEP(5, q1.y, q1.z, q1.w, q2.x)                                 \
      F1STEP(6, q1.z, q1.w, q2.x, q2.y) }

// table lerp from global (L1-resident 18KB table), named temps only
#define LERP1(res, aval, T)                                             \
    { float t_ = fminf(fmaxf(fmaf(aval, 64.f, 96.f), 0.f), 191.999f);   \
      float fj_ = floorf(t_);                                           \
      float2 e_ = (T)[(int)fj_];            /* global_load_dwordx2 */   \
      res = fmaf(t_ - fj_, e_.y, e_.x); }

// conv2 inner step (flipped weights), both channels, generic accumulators
#define C2STEPG(WI, s0, s1, s2, s3, t0, t1, t2, t3)                     \
    { float fa = wra[WI], fb = wrb[WI];                                 \
      q0 = fmaf(s0, fa, q0); q1 = fmaf(s1, fa, q1);                     \
      q2 = fmaf(s2, fa, q2); q3 = fmaf(s3, fa, q3);                     \
      q0 = fmaf(t0, fb, q0); q1 = fmaf(t1, fb, q1);                     \
      q2 = fmaf(t2, fb, q2); q3 = fmaf(t3, fb, q3); }

// full dx sweep (dx ascending 0..6 <=> WI descending 6..0, both channels)
#define C2SWEEP()                                                       \
    C2STEPG(6, A0.x, A0.y, A0.z, A0.w, B0.x, B0.y, B0.z, B0.w)          \
    C2STEPG(5, A0.y, A0.z, A0.w, A1.x, B0.y, B0.z, B0.w, B1.x)          \
    C2STEPG(4, A0.z, A0.w, A1.x, A1.y, B0.z, B0.w, B1.x, B1.y)          \
    C2STEPG(3, A0.w, A1.x, A1.y, A1.z, B0.w, B1.x, B1.y, B1.z)          \
    C2STEPG(2, A1.x, A1.y, A1.z, A1.w, B1.x, B1.y, B1.z, B1.w)          \
    C2STEPG(1, A1.y, A1.z, A1.w, A2.x, B1.y, B1.z, B1.w, B2.x)          \
    C2STEPG(0, A1.z, A1.w, A2.x, A2.y, B1.z, B1.w, B2.x, B2.y)

// ---- r21 main kernel: 2ch/block, 32x64 tile, 2x4 px/thread ----
__global__ __launch_bounds__(256, 4)
void tnrd_main_2x(const float* __restrict__ u,
                  const float* __restrict__ wf,    // filters [48][49]
                  const float2* __restrict__ tab,  // phi tables [48][TP]
                  float* __restrict__ part)
{
    __shared__ __align__(16) float u_s[UTY * USTR2];        // 14784 B
    __shared__ __align__(16) float phi_s[2][PTY * PSTR2];   // 23104 B

    const int tid = threadIdx.x;
    const int bx = blockIdx.x, by = blockIdx.y;          // 4 x 8 tiles
    const int b = blockIdx.z / 24, g = blockIdx.z % 24;
    const int c0 = g * 2;

    // ---- stage u tile (6-halo, zero-padded incl. stride pad) ----
    const int uy0 = by * OTY - 6, ux0 = bx * OTX - 6;
    const float* ub = u + b * (HH * WW);
    for (int i = tid; i < UTY * USTR2; i += 256) {
        int r = i / USTR2, c = i - r * USTR2;
        int gy = uy0 + r, gx = ux0 + c;
        float v = 0.f;
        if (c < UTX && (unsigned)gy < HH && (unsigned)gx < WW)
            v = ub[gy * WW + gx];
        u_s[i] = v;
    }
    __syncthreads();

    const int py0 = by * OTY - 3, px0 = bx * OTX - 3;

    // ---- conv1 + RBF lerp into planes phi_s[0]/phi_s[1] ----
    {
        const float* wA = wf + c0 * 49;            // block-uniform s_load
        const float* wB = wA + 49;
        const float2* tA = tab + c0 * TP;          // global, L1-hot
        const float2* tB = tA + TP;
        // 684 items = 18 col-strips x 38 rows (column-major)
        for (int p = 0; p < 3; ++p) {
            const int gi = tid + p * 256;
            if (gi < N1ITEM) {
                const int pr = gi % PTY, pc = (gi / PTY) * 4;
                float a0 = 0.f, a1 = 0.f, a2 = 0.f, a3 = 0.f;
                float b0 = 0.f, b1 = 0.f, b2 = 0.f, b3 = 0.f;
                const float* bptr = &u_s[pr * USTR2 + pc];

                // software pipeline: load row dy+1 before consuming row dy
                float4 c0v = *(const float4*)(bptr);
                float4 c1v = *(const float4*)(bptr + 4);
                float2 c2v = *(const float2*)(bptr + 8);
                #pragma unroll 1
                for (int dy = 0; dy < 6; ++dy) {
                    const float* nr = bptr + (dy + 1) * USTR2;
                    float4 n0 = *(const float4*)(nr);
                    float4 n1 = *(const float4*)(nr + 4);
                    float2 n2 = *(const float2*)(nr + 8);
                    F1ROW(wA + dy * 7, wB + dy * 7, c0v, c1v, c2v)
                    c0v = n0; c1v = n1; c2v = n2;
                }
                F1ROW(wA + 42, wB + 42, c0v, c1v, c2v)   // epilogue dy=6

                // ---- 1-gather lerp; phi = 0 outside image ----
                const int gy = py0 + pr;
                const bool rowok = (unsigned)gy < HH;
                const bool ok0 = rowok && (unsigned)(px0 + pc + 0) < WW;
                const bool ok1 = rowok && (unsigned)(px0 + pc + 1) < WW;
                const bool ok2 = rowok && (unsigned)(px0 + pc + 2) < WW;
                const bool ok3 = rowok && (unsigned)(px0 + pc + 3) < WW;
                float pA0, pA1, pA2, pA3, pB0, pB1, pB2, pB3;
                LERP1(pA0, a0, tA) LERP1(pB0, b0, tB)
                LERP1(pA1, a1, tA) LERP1(pB1, b1, tB)
                LERP1(pA2, a2, tA) LERP1(pB2, b2, tB)
                LERP1(pA3, a3, tA) LERP1(pB3, b3, tB)
                pA0 = ok0 ? pA0 : 0.f;  pB0 = ok0 ? pB0 : 0.f;
                pA1 = ok1 ? pA1 : 0.f;  pB1 = ok1 ? pB1 : 0.f;
                pA2 = ok2 ? pA2 : 0.f;  pB2 = ok2 ? pB2 : 0.f;
                pA3 = ok3 ? pA3 : 0.f;  pB3 = ok3 ? pB3 : 0.f;
                *(float4*)(&phi_s[0][pr * PSTR2 + pc]) =
                    make_float4(pA0, pA1, pA2, pA3);      // ds_write_b128
                *(float4*)(&phi_s[1][pr * PSTR2 + pc]) =
                    make_float4(pB0, pB1, pB2, pB3);      // ds_write_b128
            }
        }
    }
    __syncthreads();

    // ---- conv2: 2x4 px per thread (rows 2tr, 2tr+1; cols 4tc..4tc+3) ----
    {
        const int tr = tid >> 4;        // 0..15 -> rows 2tr, 2tr+1
        const int ox = (tid & 15) * 4;  // 0..60
        const float* wA = wf + c0 * 49;
        const float* wB = wA + 49;
        float o00 = 0.f, o01 = 0.f, o02 = 0.f, o03 = 0.f;   // row 2tr
        float o10 = 0.f, o11 = 0.f, o12 = 0.f, o13 = 0.f;   // row 2tr+1

        // tile rows 2tr+dyt, dyt=0..7; row0 uses dyt 0..6 (wrow 6-dyt),
        // row1 uses dyt 1..7 (wrow 7-dyt) -> per-acc dy order unchanged
        #pragma unroll
        for (int dyt = 0; dyt < 8; ++dyt) {
            const float* rA = &phi_s[0][(2 * tr + dyt) * PSTR2 + ox];
            const float* rB = &phi_s[1][(2 * tr + dyt) * PSTR2 + ox];
            const float4 A0 = *(const float4*)(rA);
            const float4 A1 = *(const float4*)(rA + 4);
            const float2 A2 = *(const float2*)(rA + 8);
            const float4 B0 = *(const float4*)(rB);
            const float4 B1 = *(const float4*)(rB + 4);
            const float2 B2 = *(const float2*)(rB + 8);
            if (dyt < 7) {   // accumulate output row 2tr
                const float* wra = wA + (6 - dyt) * 7;
                const float* wrb = wB + (6 - dyt) * 7;
                float &q0 = o00, &q1 = o01, &q2 = o02, &q3 = o03;
                C2SWEEP()
            }
            if (dyt > 0) {   // accumulate output row 2tr+1
                const float* wra = wA + (7 - dyt) * 7;
                const float* wrb = wB + (7 - dyt) * 7;
                float &q0 = o10, &q1 = o11, &q2 = o12, &q3 = o13;
                C2SWEEP()
            }
        }

        const int gy0 = by * OTY + 2 * tr, gx = bx * OTX + ox;
        float* dst = part + (size_t)g * NPIX + b * (HH * WW) + gy0 * WW + gx;
        *reinterpret_cast<float4*>(dst)      = make_float4(o00, o01, o02, o03);
        *reinterpret_cast<float4*>(dst + WW) = make_float4(o10, o11, o12, o13);
    }
}

// conv2 inner step for legacy kernel (fixed names o0..o3)
#define C2STEP(WI, s0, s1, s2, s3, t0, t1, t2, t3)                      \
    { float fa = wra[WI], fb = wrb[WI];                                 \
      o0 = fmaf(s0, fa, o0); o1 = fmaf(s1, fa, o1);                     \
      o2 = fmaf(s2, fa, o2); o3 = fmaf(s3, fa, o3);                     \
      o0 = fmaf(t0, fb, o0); o1 = fmaf(t1, fb, o1);                     \
      o2 = fmaf(t2, fb, o2); o3 = fmaf(t3, fb, o3); }

// ---- legacy fallback (proven r17/r20 device code), CPG=4/8 ----
template<int CPG>
__global__ __launch_bounds__(256, 6)
void tnrd_main(const float* __restrict__ u,
               const float* __restrict__ wf,
               const float2* __restrict__ tab,
               float* __restrict__ part)
{
    constexpr int NGRP = NC / CPG;
    constexpr int NPASS = CPG / 2;
    __shared__ __align__(16) float u_s[UT * USTR];
    __shared__ __align__(16) float phi_s[2][PT * PSTR];

    const int tid = threadIdx.x;
    const int bx = blockIdx.x, by = blockIdx.y;
    const int b = blockIdx.z / NGRP, g = blockIdx.z % NGRP;
    const int c0g = g * CPG;

    const int uy0 = by * OT - 6, ux0 = bx * OT - 6;
    const float* ub = u + b * (HH * WW);
    for (int i = tid; i < UT * USTR; i += 256) {
        int r = i / USTR, c = i - r * USTR;
        int gy = uy0 + r, gx = ux0 + c;
        float v = 0.f;
        if (c < UT && (unsigned)gy < HH && (unsigned)gx < WW)
            v = ub[gy * WW + gx];
        u_s[i] = v;
    }
    __syncthreads();

    const int oy = tid >> 3;
    const int ox0 = (tid & 7) * 4;
    float o0 = 0.f, o1 = 0.f, o2 = 0.f, o3 = 0.f;
    const int py0 = by * OT - 3, px0 = bx * OT - 3;

    auto conv1_pass = [&](int cp, float* __restrict__ bufA,
                          float* __restrict__ bufB) {
        const float* wA = wf + (c0g + 2 * cp) * 49;
        const float* wB = wA + 49;
        const float2* tA = tab + (c0g + 2 * cp) * TP;
        const float2* tB = tA + TP;
        for (int p = 0; p < 2; ++p) {
            const int gi = tid + p * 256;
            if (gi < PT * 10) {
                const int pr = gi % PT, pc = (gi / PT) * 4;
                float a0 = 0.f, a1 = 0.f, a2 = 0.f, a3 = 0.f;
                float b0 = 0.f, b1 = 0.f, b2 = 0.f, b3 = 0.f;
                const float* bptr = &u_s[pr * USTR + pc];
                float4 c0 = *(const float4*)(bptr);
                float4 c1 = *(const float4*)(bptr + 4);
                float2 c2 = *(const float2*)(bptr + 8);
                #pragma unroll 1
                for (int dy = 0; dy < 6; ++dy) {
                    const float* nr = bptr + (dy + 1) * USTR;
                    float4 n0 = *(const float4*)(nr);
                    float4 n1 = *(const float4*)(nr + 4);
                    float2 n2 = *(const float2*)(nr + 8);
                    F1ROW(wA + dy * 7, wB + dy * 7, c0, c1, c2)
                    c0 = n0; c1 = n1; c2 = n2;
                }
                F1ROW(wA + 42, wB + 42, c0, c1, c2)
                const int gy = py0 + pr;
                const bool rowok = (unsigned)gy < HH;
                const bool ok0 = rowok && (unsigned)(px0 + pc + 0) < WW;
                const bool ok1 = rowok && (unsigned)(px0 + pc + 1) < WW;
                const bool ok2 = rowok && (unsigned)(px0 + pc + 2) < WW;
                const bool ok3 = rowok && (unsigned)(px0 + pc + 3) < WW;
                float pA0, pA1, pA2, pA3, pB0, pB1, pB2, pB3;
                LERP1(pA0, a0, tA) LERP1(pB0, b0, tB)
                LERP1(pA1, a1, tA) LERP1(pB1, b1, tB)
                LERP1(pA2, a2, tA) LERP1(pB2, b2, tB)
                LERP1(pA3, a3, tA) LERP1(pB3, b3, tB)
                pA0 = ok0 ? pA0 : 0.f;  pB0 = ok0 ? pB0 : 0.f;
                pA1 = ok1 ? pA1 : 0.f;  pB1 = ok1 ? pB1 : 0.f;
                pA2 = ok2 ? pA2 : 0.f;  pB2 = ok2 ? pB2 : 0.f;
                pA3 = ok3 ? pA3 : 0.f;  pB3 = ok3 ? pB3 : 0.f;
                *(float4*)(bufA + pr * PSTR + pc) =
                    make_float4(pA0, pA1, pA2, pA3);
                *(float4*)(bufB + pr * PSTR + pc) =
                    make_float4(pB0, pB1, pB2, pB3);
            }
        }
    };

    #pragma unroll 1
    for (int pass = 0; pass < NPASS; ++pass) {
        conv1_pass(pass, phi_s[0], phi_s[1]);
        __syncthreads();
        const float* wA = wf + (c0g + 2 * pass) * 49;
        const float* wB = wA + 49;
        const float* pA = phi_s[0];
        const float* pB = phi_s[1];
        for (int dy = 0; dy < 7; ++dy) {
            const float* rA = pA + (oy + dy) * PSTR + ox0;
            const float* rB = pB + (oy + dy) * PSTR + ox0;
            const float4 A0 = *(const float4*)(rA);
            const float4 A1 = *(const float4*)(rA + 4);
            const float2 A2 = *(const float2*)(rA + 8);
            const float4 B0 = *(const float4*)(rB);
            const float4 B1 = *(const float4*)(rB + 4);
            const float2 B2 = *(const float2*)(rB + 8);
            const float* wra = wA + (6 - dy) * 7;
            const float* wrb = wB + (6 - dy) * 7;
            C2STEP(6, A0.x, A0.y, A0.z, A0.w, B0.x, B0.y, B0.z, B0.w)
            C2STEP(5, A0.y, A0.z, A0.w, A1.x, B0.y, B0.z, B0.w, B1.x)
            C2STEP(4, A0.z, A0.w, A1.x, A1.y, B0.z, B0.w, B1.x, B1.y)
            C2STEP(3, A0.w, A1.x, A1.y, A1.z, B0.w, B1.x, B1.y, B1.z)
            C2STEP(2, A1.x, A1.y, A1.z, A1.w, B1.x, B1.y, B1.z, B1.w)
            C2STEP(1, A1.y, A1.z, A1.w, A2.x, B1.y, B1.z, B1.w, B2.x)
            C2STEP(0, A1.z, A1.w, A2.x, A2.y, B1.z, B1.w, B2.x, B2.y)
        }
        if (pass < NPASS - 1) __syncthreads();
    }

    const int gy = by * OT + oy, gx = bx * OT + ox0;
    float4 v4 = make_float4(o0, o1, o2, o3);
    *reinterpret_cast<float4*>(part + (size_t)g * NPIX + b * (HH * WW)
                               + gy * WW + gx) = v4;
}

template<int NGRP>
__global__ __launch_bounds__(256)
void combine_kernel(const float* __restrict__ u,
                    const float* __restrict__ f,
                    const float* __restrict__ lam,
                    const float* __restrict__ part,
                    float* __restrict__ out)
{
    int i = blockIdx.x * 256 + threadIdx.x;  // 512 blocks -> NPIX
    float d = 0.f;
    #pragma unroll
    for (int g = 0; g < NGRP; ++g) d += part[g * NPIX + i];
    float lv = lam[0];
    float uv = u[i];
    float fv = f[i];
    out[i] = uv - d - lv * (uv - fv);
}

extern "C" void kernel_launch(void* const* d_in, const int* in_sizes, int n_in,
                              void* d_out, int out_size, void* d_ws, size_t ws_size,
                              hipStream_t stream) {
    const float* u    = (const float*)d_in[0];
    const float* f    = (const float*)d_in[1];
    const float* filt = (const float*)d_in[2];
    const float* rbfw = (const float*)d_in[3];
    const float* lam  = (const float*)d_in[4];
    float* out = (float*)d_out;
    float* part = (float*)d_ws;
    // phi tables overlaid on d_out scratch (48*192 float2 = 18432 floats
    // <= 131072); combine_kernel fully overwrites d_out afterwards.
    float2* tabg = (float2*)d_out;

    tnrd_table<<<NC, 256, 0, stream>>>(rbfw, tabg);
    if (ws_size >= (size_t)24 * NPIX * sizeof(float)) {
        // 24 groups x 2ch, 32x64 tiles, 2x4 px/thread: 1536 blocks
        tnrd_main_2x<<<dim3(WW / OTX, HH / OTY, 48), 256, 0, stream>>>(
            u, filt, tabg, part);
        combine_kernel<24><<<512, 256, 0, stream>>>(u, f, lam, part, out);
    } else if (ws_size >= (size_t)12 * NPIX * sizeof(float)) {
        // r17 structure: 12 groups x 4ch, 6 blocks/CU
        tnrd_main<4><<<dim3(8, 8, 24), 256, 0, stream>>>(u, filt, tabg, part);
        combine_kernel<12><<<512, 256, 0, stream>>>(u, f, lam, part, out);
    } else {
        // smallest-ws fallback: 6 groups x 8ch (r15 structure)
        tnrd_main<8><<<dim3(8, 8, 12), 256, 0, stream>>>(u, filt, tabg, part);
        combine_kernel<6><<<512, 256, 0, stream>>>(u, f, lam, part, out);
    }
}